// Round 11
// baseline (628.448 us; speedup 1.0000x reference)
//
#include <hip/hip_runtime.h>
#include <cstdint>
#include <cstddef>

#define NNODES 50000
#define NEDGES 800000
#define INDIM  256
#define HD     128   // H*D
#define NH     4
#define NEG    0.2f
#define LOG2E  1.44269504088896340736f

#define SCAN_B ((NNODES + 255) / 256)   // 196 blocks

// fusedPre partition (clear cnt | conv_w | clear flags)
#define CLR_BLKS   49                               // 12544 int4 slots >= 12500
#define CONVW_BLKS 64
// hist
#define HIST_BLKS  ((NEDGES + 2047) / 2048)         // 391
// fusedB block partition (gemm 128x256 | scatter 8 edges/thread)
#define GEMM_BLKS  ((NNODES + 127) / 128)           // 391
#define SCAT_BLKS  ((NEDGES + 2047) / 2048)         // 391

typedef __attribute__((ext_vector_type(8))) short   short8;   // 8 bf16 (4 VGPRs)
typedef __attribute__((ext_vector_type(8))) ushort  ushort8;
typedef __attribute__((ext_vector_type(4))) float   floatx4;

// f32 -> bf16 (round-to-nearest-even), raw bits
__device__ __forceinline__ ushort f2bf(float f) {
    unsigned u = __float_as_uint(f);
    unsigned r = u + 0x7fffu + ((u >> 16) & 1u);
    return (ushort)(r >> 16);
}
__device__ __forceinline__ float bf2f(ushort u) {
    return __uint_as_float(((unsigned)u) << 16);
}

// LDS chunk swizzle: conflict-free staging writes + fragment reads
__device__ __forceinline__ int swz(int c) { return c ^ ((c >> 4) & 7); }

// ================= fusedPre: clear cnt | clear flags+ticket | W convert+transpose ====
// Cross-launch ordering (this kernel completes before hist/scan start) makes the
// clears safe; no same-kernel ordering is relied upon. Re-runs every launch, so the
// scan's flags/ticket are reset for every timing replay.
__global__ __launch_bounds__(256) void fusedPre_kernel(
        int* __restrict__ cnt_work, int* __restrict__ flags,
        const float* __restrict__ Wsrc, const float* __restrict__ Wdst,
        ushort* __restrict__ Wt) {
    __shared__ float t[32][33];
    const int bid = blockIdx.x;
    const int tid = threadIdx.x;

    if (bid < CLR_BLKS) {
        int i = bid * 256 + tid;
        if (i < (NNODES + 3) / 4)
            ((int4*)cnt_work)[i] = make_int4(0, 0, 0, 0);
        return;
    }
    if (bid == CLR_BLKS + CONVW_BLKS) {
        // clear flags[SCAN_B] + ticket (1)
        if (tid < SCAN_B + 1) flags[tid] = 0;
        return;
    }
    // ---- W convert+transpose (LDS-tiled): Wt[n][k] bf16 ----
    int wb = bid - CLR_BLKS;                      // 0..63
    int kb = (wb & 7) * 32, nb = (wb >> 3) * 32;
    int tx = tid & 31, ty = tid >> 5;
    for (int i = ty; i < 32; i += 8) {
        int k = kb + i, n = nb + tx;
        float v = (n < HD) ? Wsrc[(size_t)k * HD + n] : Wdst[(size_t)k * HD + (n - HD)];
        t[i][tx] = v;
    }
    __syncthreads();
    for (int i = ty; i < 32; i += 8) {
        int n = nb + i, k = kb + tx;
        Wt[(size_t)n * INDIM + k] = f2bf(t[tx][i]);
    }
}

// ================= hist: 8 edges/thread, non-returning atomics =================
__global__ __launch_bounds__(256) void hist_kernel(
        const int* __restrict__ dst, int* __restrict__ cnt_work) {
    int base = blockIdx.x * 2048 + threadIdx.x;
    int dd[8];
#pragma unroll
    for (int k = 0; k < 8; ++k) {
        int e = base + k * 256;
        dd[k] = (e < NEDGES) ? dst[e] : -1;
    }
#pragma unroll
    for (int k = 0; k < 8; ++k) {
        if (dd[k] >= 0) atomicAdd(cnt_work + dd[k], 1);
    }
}

// ================= scan_lb: single-kernel decoupled-lookback exclusive scan =========
// Ticket-ordered: each block takes a ticket; block t spins only on flag[t-1], which
// was taken by an already-running (or finished) block -> deadlock-free regardless of
// dispatch order (chain terminates at tile 0, which never spins; 196 blocks are all
// co-resident on 256 CUs anyway). flag[t] stores (inclusive-total-through-tile-t)+1
// (0 = unset), device-scope release/acquire for cross-XCD visibility. s_sleep in the
// spin keeps the waiting wave off the memory pipes.
__global__ __launch_bounds__(256) void scan_lb_kernel(
        int* __restrict__ cnt_work, int* __restrict__ rowptr,
        int* __restrict__ flags, int* __restrict__ ticket) {
    __shared__ int lds[256];
    __shared__ int sh_tile, sh_prefix;
    const int t = threadIdx.x;

    if (t == 0) sh_tile = atomicAdd(ticket, 1);
    __syncthreads();
    const int tile = sh_tile;
    const int i = tile * 256 + t;

    int v = (i < NNODES) ? cnt_work[i] : 0;
    lds[t] = v;
    __syncthreads();
    for (int off = 1; off < 256; off <<= 1) {
        int u = (t >= off) ? lds[t - off] : 0;
        __syncthreads();
        lds[t] += u;
        __syncthreads();
    }
    const int excl = lds[t] - v;
    const int bsum = lds[255];

    if (t == 0) {
        int prefix = 0;
        if (tile > 0) {
            int f;
            while ((f = __hip_atomic_load(&flags[tile - 1], __ATOMIC_ACQUIRE,
                                          __HIP_MEMORY_SCOPE_AGENT)) == 0) {
                __builtin_amdgcn_s_sleep(1);
            }
            prefix = f - 1;
        }
        sh_prefix = prefix;
        __hip_atomic_store(&flags[tile], prefix + bsum + 1, __ATOMIC_RELEASE,
                           __HIP_MEMORY_SCOPE_AGENT);
    }
    __syncthreads();
    const int prefix = sh_prefix;

    if (i < NNODES) {
        int start = prefix + excl;
        rowptr[i] = start;
        cnt_work[i] = start;          // scatter cursor
    }
    if (tile == SCAN_B - 1 && t == 255) rowptr[NNODES] = prefix + bsum;
}

// ================= fusedB: MFMA GEMM (128x256, f32 A direct) | CSR scatter =========
// A read once (f32 h, f2bf in staging -> bit-identical to a pre-converted path).
// Scatter: 8 edges/thread, returning atomics on cnt_work cursors, packed int2 store
// into the DENSE CSR epair region (full-line writes; bucket layout's partial-line
// RMW cost ~60us extra -- measured r9, do not bring buckets back).
__global__ __launch_bounds__(256, 2) void fusedB_kernel(
        const float* __restrict__ h, const ushort* __restrict__ Wt,
        const float* __restrict__ bsrc, const float* __restrict__ bdst,
        ushort* __restrict__ el_bf, float* __restrict__ er,
        const int* __restrict__ src, const int* __restrict__ dst,
        int* __restrict__ cnt_work, int2* __restrict__ epair) {
    __shared__ ushort As[512 * 8];    // 128 rows x 32 k bf16 (8 KB)
    __shared__ ushort Bs[1024 * 8];   // 256 cols x 32 k bf16 (16 KB)

    const int bid = blockIdx.x;
    const int tid = threadIdx.x;

    if (bid >= GEMM_BLKS) {
        // ---- scatter: build CSR edge list, 8 edges/thread (stride-256, coalesced) ----
        int base = (bid - GEMM_BLKS) * 2048 + tid;
        int ss[8], dd[8], pos[8];
#pragma unroll
        for (int k = 0; k < 8; ++k) {
            int e = base + k * 256;
            if (e < NEDGES) { ss[k] = src[e]; dd[k] = dst[e]; } else dd[k] = -1;
        }
#pragma unroll
        for (int k = 0; k < 8; ++k) {
            if (dd[k] >= 0) pos[k] = atomicAdd(cnt_work + dd[k], 1);
        }
#pragma unroll
        for (int k = 0; k < 8; ++k) {
            int e = base + k * 256;
            if (dd[k] >= 0) epair[pos[k]] = make_int2(e, ss[k]);
        }
        return;
    }

    const int wave = tid >> 6, lane = tid & 63;
    const int row0 = bid * 128;
    const int l15  = lane & 15, quad = lane >> 4;

    floatx4 acc[2][16];
#pragma unroll
    for (int i = 0; i < 2; ++i)
#pragma unroll
        for (int j = 0; j < 16; ++j) acc[i][j] = (floatx4){0.f, 0.f, 0.f, 0.f};

    for (int kk = 0; kk < INDIM; kk += 32) {
        // ---- A staging: 512 chunks of 8, f32 source + convert ----
#pragma unroll
        for (int it = 0; it < 2; ++it) {
            int idx = tid + it * 256;    // 0..511
            int r = idx >> 2;            // 0..127 (row)
            int kq = idx & 3;            // k-quad (8 elems)
            int c = (r >> 4) * 64 + kq * 16 + (r & 15);
            int grow = row0 + r;
            ushort8 aw = (ushort8){0,0,0,0,0,0,0,0};
            if (grow < NNODES) {
                const float* p = h + (size_t)grow * INDIM + kk + kq * 8;
                float4 v0 = *(const float4*)p;
                float4 v1 = *(const float4*)(p + 4);
                aw[0] = f2bf(v0.x); aw[1] = f2bf(v0.y); aw[2] = f2bf(v0.z); aw[3] = f2bf(v0.w);
                aw[4] = f2bf(v1.x); aw[5] = f2bf(v1.y); aw[6] = f2bf(v1.z); aw[7] = f2bf(v1.w);
            }
            *(ushort8*)(As + swz(c) * 8) = aw;
        }
        // ---- B staging: 1024 chunks of 8 (256 cols) ----
#pragma unroll
        for (int it = 0; it < 4; ++it) {
            int idx = tid + it * 256;    // 0..1023
            int r = idx >> 2;            // 0..255 (col)
            int kq = idx & 3;
            int c = (r >> 4) * 64 + kq * 16 + (r & 15);   // 0..1023
            ushort8 bw = *(const ushort8*)(Wt + (size_t)r * INDIM + kk + kq * 8);
            *(ushort8*)(Bs + swz(c) * 8) = bw;
        }
        __syncthreads();

        short8 af[2];
#pragma unroll
        for (int tm = 0; tm < 2; ++tm) {
            int c = (wave * 2 + tm) * 64 + quad * 16 + l15;
            af[tm] = *(const short8*)(As + swz(c) * 8);
        }
#pragma unroll
        for (int tn = 0; tn < 16; ++tn) {
            int c = tn * 64 + quad * 16 + l15;
            short8 bfr = *(const short8*)(Bs + swz(c) * 8);
            acc[0][tn] = __builtin_amdgcn_mfma_f32_16x16x32_bf16(af[0], bfr, acc[0][tn], 0, 0, 0);
            acc[1][tn] = __builtin_amdgcn_mfma_f32_16x16x32_bf16(af[1], bfr, acc[1][tn], 0, 0, 0);
        }
        __syncthreads();
    }

    // epilogue: C/D layout col=lane&15, row=quad*4+reg
#pragma unroll
    for (int tn = 0; tn < 8; ++tn) {
        int col = tn * 16 + l15;              // 0..127 -> el
        float bias = bsrc[col];
#pragma unroll
        for (int tm = 0; tm < 2; ++tm)
#pragma unroll
            for (int reg = 0; reg < 4; ++reg) {
                int row = row0 + wave * 32 + tm * 16 + quad * 4 + reg;
                if (row < NNODES)
                    el_bf[(size_t)row * HD + col] = f2bf(acc[tm][tn][reg] + bias);
            }
    }
#pragma unroll
    for (int tn = 8; tn < 16; ++tn) {
        int col = tn * 16 + l15 - HD;         // 0..127 -> er
        float bias = bdst[col];
#pragma unroll
        for (int tm = 0; tm < 2; ++tm)
#pragma unroll
            for (int reg = 0; reg < 4; ++reg) {
                int row = row0 + wave * 32 + tm * 16 + quad * 4 + reg;
                if (row < NNODES)
                    er[(size_t)row * HD + col] = acc[tm][tn][reg] + bias;
            }
    }
}

// ================= node_fused: r5-proven branchless body + exp2 rebasing ===========
// one wave per node; lane l owns dims 2l,2l+1; head hh = l>>4. CSR int2 epair.
// exp2 rebasing: a0,a1 pre-scaled by log2(e) -> scores live in log2 domain; every
// __expf(x) becomes exp2f(x) (v_exp_f32 directly, saves the hidden *1.4427 mul).
// Body shape is the proven 71-73us form -- do NOT restructure (two batched rewrites
// and defer-max all regressed; buckets regressed; this exact shape is load-bearing).
#define DEGCAP 128

__global__ __launch_bounds__(256) void node_fused_kernel(
        const ushort* __restrict__ el_bf, const float* __restrict__ er,
        const int* __restrict__ rowptr, const int2* __restrict__ epair,
        const float* __restrict__ attn,
        float* __restrict__ out_feat, float* __restrict__ out_a) {
    __shared__ float sp[4][DEGCAP * NH];   // 2 KB per wave

    const int wv = threadIdx.x >> 6;
    const int n = blockIdx.x * 4 + wv;
    if (n >= NNODES) return;
    const int lane = threadIdx.x & 63;
    const int hh = lane >> 4;
    const int lo = rowptr[n], hi = rowptr[n + 1];
    const int deg = hi - lo;
    float* spw = sp[wv];
    const int l2 = lane * 2;

    const float2 rv = *(const float2*)(er + (size_t)n * HD + l2);
    const float a0 = attn[l2] * LOG2E, a1 = attn[l2 + 1] * LOG2E;

    float m = -3.4e38f, lsum = 0.0f, acc0 = 0.0f, acc1 = 0.0f;

    if (deg > 0 && deg <= DEGCAP) {
        // preload first chunk of up to 16 edge-source indices (coalesced, clamped)
        int jj0 = (lane & 15);
        if (jj0 >= deg) jj0 = deg - 1;
        int si = epair[lo + jj0].y;

        for (int base = 0; base < deg; base += 16) {
            // issue all gathers of this chunk (wave-uniform scalar base per edge)
            ushort2 u[16];
#pragma unroll
            for (int j = 0; j < 16; ++j) {
                if (base + j < deg) {
                    int s = __builtin_amdgcn_readlane(si, j);
                    u[j] = *(const ushort2*)(el_bf + (size_t)s * HD + l2);
                }
            }
            // prefetch next chunk's indices (hides index-load latency under compute)
            int si_nxt = si;
            if (base + 16 < deg) {
                int jj = base + 16 + (lane & 15);
                if (jj >= deg) jj = deg - 1;
                si_nxt = epair[lo + jj].y;
            }
            // process chunk: per-edge, branchless online softmax (proven shape)
#pragma unroll
            for (int j = 0; j < 16; ++j) {
                if (base + j < deg) {
                    float evx = bf2f(u[j].x), evy = bf2f(u[j].y);
                    float x0 = evx + rv.x; x0 = fmaxf(x0, NEG * x0);
                    float x1 = evy + rv.y; x1 = fmaxf(x1, NEG * x1);
                    float p = x0 * a0 + x1 * a1;        // log2-domain score
                    p += __shfl_xor(p, 1, 16);
                    p += __shfl_xor(p, 2, 16);
                    p += __shfl_xor(p, 4, 16);
                    p += __shfl_xor(p, 8, 16);
                    if ((lane & 15) == 0) spw[(base + j) * NH + hh] = p;
                    float mn = fmaxf(m, p);
                    float sc = exp2f(m - mn);
                    float w  = exp2f(p - mn);
                    lsum = lsum * sc + w;
                    acc0 = acc0 * sc + w * evx;
                    acc1 = acc1 * sc + w * evy;
                    m = mn;
                }
            }
            si = si_nxt;
        }
    } else if (deg > DEGCAP) {
        // fallback pass 1: online softmax only (no score stash)
        ushort2 u = {0,0};
        { int s_ = epair[lo].y; u = *(const ushort2*)(el_bf + (size_t)s_ * HD + l2); }
        for (int i = lo; i < hi; ++i) {
            float evx = bf2f(u.x), evy = bf2f(u.y);
            if (i + 1 < hi) { int s_ = epair[i + 1].y;
                u = *(const ushort2*)(el_bf + (size_t)s_ * HD + l2); }
            float x0 = evx + rv.x; x0 = fmaxf(x0, NEG * x0);
            float x1 = evy + rv.y; x1 = fmaxf(x1, NEG * x1);
            float p = x0 * a0 + x1 * a1;
            p += __shfl_xor(p, 1, 16);
            p += __shfl_xor(p, 2, 16);
            p += __shfl_xor(p, 4, 16);
            p += __shfl_xor(p, 8, 16);
            float mn = fmaxf(m, p);
            float sc = exp2f(m - mn);
            float w  = exp2f(p - mn);
            lsum = lsum * sc + w;
            acc0 = acc0 * sc + w * evx;
            acc1 = acc1 * sc + w * evy;
            m = mn;
        }
    }

    // write aggregated features
    float2 o;
    if (deg == 0) { o.x = 0.0f; o.y = 0.0f; }
    else { float inv = 1.0f / lsum; o.x = acc0 * inv; o.y = acc1 * inv; }
    *(float2*)(out_feat + (size_t)n * HD + l2) = o;

    if (deg == 0) return;

    // normalize + write attention weights
    float inv = 1.0f / lsum;
    if (deg <= DEGCAP) {
        // broadcast (m, inv) of head (lane&3) from its group (values uniform in group)
        float mh   = __shfl(m,   (lane & 3) << 4, 64);
        float invh = __shfl(inv, (lane & 3) << 4, 64);
        for (int q = (lane >> 2); q < deg; q += 16) {
            int e = epair[lo + q].x;
            float p = spw[q * NH + (lane & 3)];
            out_a[(size_t)e * NH + (lane & 3)] = exp2f(p - mh) * invh;
        }
    } else {
        // fallback pass 2: recompute scores and write a
        for (int i = lo; i < hi; ++i) {
            int s_ = epair[i].y;
            ushort2 u = *(const ushort2*)(el_bf + (size_t)s_ * HD + l2);
            float evx = bf2f(u.x), evy = bf2f(u.y);
            float x0 = evx + rv.x; x0 = fmaxf(x0, NEG * x0);
            float x1 = evy + rv.y; x1 = fmaxf(x1, NEG * x1);
            float p = x0 * a0 + x1 * a1;
            p += __shfl_xor(p, 1, 16);
            p += __shfl_xor(p, 2, 16);
            p += __shfl_xor(p, 4, 16);
            p += __shfl_xor(p, 8, 16);
            if ((lane & 15) == 0) {
                int e = epair[i].x;
                out_a[(size_t)e * NH + hh] = exp2f(p - m) * inv;
            }
        }
    }
}

extern "C" void kernel_launch(void* const* d_in, const int* in_sizes, int n_in,
                              void* d_out, int out_size, void* d_ws, size_t ws_size,
                              hipStream_t stream) {
    const float* h    = (const float*)d_in[0];
    const int*   src  = (const int*)d_in[1];
    const int*   dst  = (const int*)d_in[2];
    const float* Wsrc = (const float*)d_in[3];
    const float* bsrc = (const float*)d_in[4];
    const float* Wdst = (const float*)d_in[5];
    const float* bdst = (const float*)d_in[6];
    const float* attn = (const float*)d_in[7];

    float* out_feat = (float*)d_out;                       // N*128
    float* out_a    = out_feat + (size_t)NNODES * HD;      // E*4

    // workspace layout (16B-aligned chunks), ~45 MB total
    float*  er       = (float*)d_ws;                         // N*128 f32 (25.6 MB)
    ushort* Wt       = (ushort*)(er + (size_t)NNODES * HD);  // 256*256 bf16
    ushort* el_bf    = Wt + 2 * HD * INDIM;                  // N*128 bf16 (12.8 MB)
    int*    cnt_work = (int*)(el_bf + (size_t)NNODES * HD);  // N
    int2*   epair    = (int2*)(cnt_work + NNODES);           // E {eidx, esrc} (6.4 MB)
    int*    rowptr   = (int*)(epair + NEDGES);               // N+1
    int*    flags    = rowptr + NNODES + 1;                  // SCAN_B
    int*    ticket   = flags + SCAN_B;                       // 1

    // 1) fusedPre: clear cnt | clear flags+ticket | W convert+transpose
    fusedPre_kernel<<<CLR_BLKS + CONVW_BLKS + 1, 256, 0, stream>>>(
        cnt_work, flags, Wsrc, Wdst, Wt);

    // 2) hist (non-returning atomics)
    hist_kernel<<<HIST_BLKS, 256, 0, stream>>>(dst, cnt_work);

    // 3) single-kernel decoupled-lookback scan -> rowptr + scatter cursors
    scan_lb_kernel<<<SCAN_B, 256, 0, stream>>>(cnt_work, rowptr, flags, ticket);

    // 4) fusedB: MFMA GEMM 128x256 (el, er) | CSR scatter
    fusedB_kernel<<<GEMM_BLKS + SCAT_BLKS, 256, 0, stream>>>(
        h, Wt, bsrc, bdst, el_bf, er, src, dst, cnt_work, epair);

    // 5) node_fused
    node_fused_kernel<<<(NNODES + 3) / 4, 256, 0, stream>>>(
        el_bf, er, rowptr, epair, attn, out_feat, out_a);
}

// Round 12
// 278.674 us; speedup vs baseline: 2.2551x; 2.2551x over previous
//
#include <hip/hip_runtime.h>
#include <cstdint>
#include <cstddef>

#define NNODES 50000
#define NEDGES 800000
#define INDIM  256
#define HD     128   // H*D
#define NH     4
#define NEG    0.2f
#define LOG2E  1.44269504088896340736f

#define SCAN_B ((NNODES + 255) / 256)   // 196 blocks

// fusedPre partition (clear cnt | conv_w)
#define CLR_BLKS   49                               // 12544 int4 slots >= 12500
#define CONVW_BLKS 64
// hist
#define HIST_BLKS  ((NEDGES + 2047) / 2048)         // 391
// fusedB block partition (gemm 128x256 | scatter 8 edges/thread)
#define GEMM_BLKS  ((NNODES + 127) / 128)           // 391
#define SCAT_BLKS  ((NEDGES + 2047) / 2048)         // 391

typedef __attribute__((ext_vector_type(8))) short   short8;   // 8 bf16 (4 VGPRs)
typedef __attribute__((ext_vector_type(8))) ushort  ushort8;
typedef __attribute__((ext_vector_type(4))) float   floatx4;

// f32 -> bf16 (round-to-nearest-even), raw bits
__device__ __forceinline__ ushort f2bf(float f) {
    unsigned u = __float_as_uint(f);
    unsigned r = u + 0x7fffu + ((u >> 16) & 1u);
    return (ushort)(r >> 16);
}
__device__ __forceinline__ float bf2f(ushort u) {
    return __uint_as_float(((unsigned)u) << 16);
}

// LDS chunk swizzle: conflict-free staging writes + fragment reads
__device__ __forceinline__ int swz(int c) { return c ^ ((c >> 4) & 7); }

// ================= fusedPre: clear cnt | W convert+transpose =================
// Cross-launch ordering (this kernel completes before hist starts) makes the clear
// safe; no same-kernel ordering is relied upon.
__global__ __launch_bounds__(256) void fusedPre_kernel(
        int* __restrict__ cnt_work,
        const float* __restrict__ Wsrc, const float* __restrict__ Wdst,
        ushort* __restrict__ Wt) {
    __shared__ float t[32][33];
    const int bid = blockIdx.x;
    const int tid = threadIdx.x;

    if (bid < CLR_BLKS) {
        int i = bid * 256 + tid;
        if (i < (NNODES + 3) / 4)
            ((int4*)cnt_work)[i] = make_int4(0, 0, 0, 0);
        return;
    }
    // ---- W convert+transpose (LDS-tiled): Wt[n][k] bf16 ----
    int wb = bid - CLR_BLKS;                      // 0..63
    int kb = (wb & 7) * 32, nb = (wb >> 3) * 32;
    int tx = tid & 31, ty = tid >> 5;
    for (int i = ty; i < 32; i += 8) {
        int k = kb + i, n = nb + tx;
        float v = (n < HD) ? Wsrc[(size_t)k * HD + n] : Wdst[(size_t)k * HD + (n - HD)];
        t[i][tx] = v;
    }
    __syncthreads();
    for (int i = ty; i < 32; i += 8) {
        int n = nb + i, k = kb + tx;
        Wt[(size_t)n * INDIM + k] = f2bf(t[tx][i]);
    }
}

// ================= hist: 8 edges/thread, non-returning atomics =================
__global__ __launch_bounds__(256) void hist_kernel(
        const int* __restrict__ dst, int* __restrict__ cnt_work) {
    int base = blockIdx.x * 2048 + threadIdx.x;
    int dd[8];
#pragma unroll
    for (int k = 0; k < 8; ++k) {
        int e = base + k * 256;
        dd[k] = (e < NEDGES) ? dst[e] : -1;
    }
#pragma unroll
    for (int k = 0; k < 8; ++k) {
        if (dd[k] >= 0) atomicAdd(cnt_work + dd[k], 1);
    }
}

// ================= CSR scans: proven 3-kernel chain (~13us total) =================
// (r11's single-kernel "lookback" scan was a serial chain of 196 cross-XCD
//  release/acquire hops = 375us. Reverted. Do not replace this chain again
//  without implementing true aggregate-publishing decoupled lookback.)
__global__ __launch_bounds__(256) void scan_partial_kernel(
        const int* __restrict__ cnt, int* __restrict__ partials) {
    __shared__ int lds[256];
    int i = blockIdx.x * 256 + threadIdx.x;
    lds[threadIdx.x] = (i < NNODES) ? cnt[i] : 0;
    __syncthreads();
    for (int off = 128; off > 0; off >>= 1) {
        if (threadIdx.x < off) lds[threadIdx.x] += lds[threadIdx.x + off];
        __syncthreads();
    }
    if (threadIdx.x == 0) partials[blockIdx.x] = lds[0];
}

__global__ __launch_bounds__(256) void scan_offsets_kernel(
        int* __restrict__ partials, int* __restrict__ rowptr) {
    __shared__ int lds[256];
    int t = threadIdx.x;
    int v = (t < SCAN_B) ? partials[t] : 0;
    lds[t] = v;
    __syncthreads();
    for (int off = 1; off < 256; off <<= 1) {
        int u = (t >= off) ? lds[t - off] : 0;
        __syncthreads();
        lds[t] += u;
        __syncthreads();
    }
    if (t < SCAN_B) partials[t] = lds[t] - v;      // exclusive
    if (t == 255) rowptr[NNODES] = lds[255];       // total
}

__global__ __launch_bounds__(256) void scan_final_kernel(
        int* __restrict__ cnt_work, const int* __restrict__ partials,
        int* __restrict__ rowptr) {
    __shared__ int lds[256];
    int i = blockIdx.x * 256 + threadIdx.x;
    int t = threadIdx.x;
    int v = (i < NNODES) ? cnt_work[i] : 0;
    lds[t] = v;
    __syncthreads();
    for (int off = 1; off < 256; off <<= 1) {
        int u = (t >= off) ? lds[t - off] : 0;
        __syncthreads();
        lds[t] += u;
        __syncthreads();
    }
    if (i < NNODES) {
        int start = partials[blockIdx.x] + lds[t] - v;
        rowptr[i] = start;
        cnt_work[i] = start;          // scatter cursor
    }
}

// ================= fusedB: MFMA GEMM (128x256, f32 A direct) | CSR scatter =========
// A read once (f32 h, f2bf in staging -> bit-identical to a pre-converted path).
// Scatter: 8 edges/thread, returning atomics on cnt_work cursors, packed int2 store
// into the DENSE CSR epair region (full-line writes; bucket layout's partial-line
// RMW cost ~60us extra -- measured r9, do not bring buckets back).
__global__ __launch_bounds__(256, 2) void fusedB_kernel(
        const float* __restrict__ h, const ushort* __restrict__ Wt,
        const float* __restrict__ bsrc, const float* __restrict__ bdst,
        ushort* __restrict__ el_bf, float* __restrict__ er,
        const int* __restrict__ src, const int* __restrict__ dst,
        int* __restrict__ cnt_work, int2* __restrict__ epair) {
    __shared__ ushort As[512 * 8];    // 128 rows x 32 k bf16 (8 KB)
    __shared__ ushort Bs[1024 * 8];   // 256 cols x 32 k bf16 (16 KB)

    const int bid = blockIdx.x;
    const int tid = threadIdx.x;

    if (bid >= GEMM_BLKS) {
        // ---- scatter: build CSR edge list, 8 edges/thread (stride-256, coalesced) ----
        int base = (bid - GEMM_BLKS) * 2048 + tid;
        int ss[8], dd[8], pos[8];
#pragma unroll
        for (int k = 0; k < 8; ++k) {
            int e = base + k * 256;
            if (e < NEDGES) { ss[k] = src[e]; dd[k] = dst[e]; } else dd[k] = -1;
        }
#pragma unroll
        for (int k = 0; k < 8; ++k) {
            if (dd[k] >= 0) pos[k] = atomicAdd(cnt_work + dd[k], 1);
        }
#pragma unroll
        for (int k = 0; k < 8; ++k) {
            int e = base + k * 256;
            if (dd[k] >= 0) epair[pos[k]] = make_int2(e, ss[k]);
        }
        return;
    }

    const int wave = tid >> 6, lane = tid & 63;
    const int row0 = bid * 128;
    const int l15  = lane & 15, quad = lane >> 4;

    floatx4 acc[2][16];
#pragma unroll
    for (int i = 0; i < 2; ++i)
#pragma unroll
        for (int j = 0; j < 16; ++j) acc[i][j] = (floatx4){0.f, 0.f, 0.f, 0.f};

    for (int kk = 0; kk < INDIM; kk += 32) {
        // ---- A staging: 512 chunks of 8, f32 source + convert ----
#pragma unroll
        for (int it = 0; it < 2; ++it) {
            int idx = tid + it * 256;    // 0..511
            int r = idx >> 2;            // 0..127 (row)
            int kq = idx & 3;            // k-quad (8 elems)
            int c = (r >> 4) * 64 + kq * 16 + (r & 15);
            int grow = row0 + r;
            ushort8 aw = (ushort8){0,0,0,0,0,0,0,0};
            if (grow < NNODES) {
                const float* p = h + (size_t)grow * INDIM + kk + kq * 8;
                float4 v0 = *(const float4*)p;
                float4 v1 = *(const float4*)(p + 4);
                aw[0] = f2bf(v0.x); aw[1] = f2bf(v0.y); aw[2] = f2bf(v0.z); aw[3] = f2bf(v0.w);
                aw[4] = f2bf(v1.x); aw[5] = f2bf(v1.y); aw[6] = f2bf(v1.z); aw[7] = f2bf(v1.w);
            }
            *(ushort8*)(As + swz(c) * 8) = aw;
        }
        // ---- B staging: 1024 chunks of 8 (256 cols) ----
#pragma unroll
        for (int it = 0; it < 4; ++it) {
            int idx = tid + it * 256;    // 0..1023
            int r = idx >> 2;            // 0..255 (col)
            int kq = idx & 3;
            int c = (r >> 4) * 64 + kq * 16 + (r & 15);   // 0..1023
            ushort8 bw = *(const ushort8*)(Wt + (size_t)r * INDIM + kk + kq * 8);
            *(ushort8*)(Bs + swz(c) * 8) = bw;
        }
        __syncthreads();

        short8 af[2];
#pragma unroll
        for (int tm = 0; tm < 2; ++tm) {
            int c = (wave * 2 + tm) * 64 + quad * 16 + l15;
            af[tm] = *(const short8*)(As + swz(c) * 8);
        }
#pragma unroll
        for (int tn = 0; tn < 16; ++tn) {
            int c = tn * 64 + quad * 16 + l15;
            short8 bfr = *(const short8*)(Bs + swz(c) * 8);
            acc[0][tn] = __builtin_amdgcn_mfma_f32_16x16x32_bf16(af[0], bfr, acc[0][tn], 0, 0, 0);
            acc[1][tn] = __builtin_amdgcn_mfma_f32_16x16x32_bf16(af[1], bfr, acc[1][tn], 0, 0, 0);
        }
        __syncthreads();
    }

    // epilogue: C/D layout col=lane&15, row=quad*4+reg
#pragma unroll
    for (int tn = 0; tn < 8; ++tn) {
        int col = tn * 16 + l15;              // 0..127 -> el
        float bias = bsrc[col];
#pragma unroll
        for (int tm = 0; tm < 2; ++tm)
#pragma unroll
            for (int reg = 0; reg < 4; ++reg) {
                int row = row0 + wave * 32 + tm * 16 + quad * 4 + reg;
                if (row < NNODES)
                    el_bf[(size_t)row * HD + col] = f2bf(acc[tm][tn][reg] + bias);
            }
    }
#pragma unroll
    for (int tn = 8; tn < 16; ++tn) {
        int col = tn * 16 + l15 - HD;         // 0..127 -> er
        float bias = bdst[col];
#pragma unroll
        for (int tm = 0; tm < 2; ++tm)
#pragma unroll
            for (int reg = 0; reg < 4; ++reg) {
                int row = row0 + wave * 32 + tm * 16 + quad * 4 + reg;
                if (row < NNODES)
                    er[(size_t)row * HD + col] = acc[tm][tn][reg] + bias;
            }
    }
}

// ================= node_fused: r5-proven branchless body + exp2 rebasing ===========
// one wave per node; lane l owns dims 2l,2l+1; head hh = l>>4. CSR int2 epair.
// exp2 rebasing: a0,a1 pre-scaled by log2(e) -> scores live in log2 domain; every
// __expf(x) becomes exp2f(x) (v_exp_f32 directly, saves the hidden *1.4427 mul).
// Body shape is the proven 71-73us form -- do NOT restructure (two batched rewrites
// and defer-max all regressed; buckets regressed; this exact shape is load-bearing).
#define DEGCAP 128

__global__ __launch_bounds__(256) void node_fused_kernel(
        const ushort* __restrict__ el_bf, const float* __restrict__ er,
        const int* __restrict__ rowptr, const int2* __restrict__ epair,
        const float* __restrict__ attn,
        float* __restrict__ out_feat, float* __restrict__ out_a) {
    __shared__ float sp[4][DEGCAP * NH];   // 2 KB per wave

    const int wv = threadIdx.x >> 6;
    const int n = blockIdx.x * 4 + wv;
    if (n >= NNODES) return;
    const int lane = threadIdx.x & 63;
    const int hh = lane >> 4;
    const int lo = rowptr[n], hi = rowptr[n + 1];
    const int deg = hi - lo;
    float* spw = sp[wv];
    const int l2 = lane * 2;

    const float2 rv = *(const float2*)(er + (size_t)n * HD + l2);
    const float a0 = attn[l2] * LOG2E, a1 = attn[l2 + 1] * LOG2E;

    float m = -3.4e38f, lsum = 0.0f, acc0 = 0.0f, acc1 = 0.0f;

    if (deg > 0 && deg <= DEGCAP) {
        // preload first chunk of up to 16 edge-source indices (coalesced, clamped)
        int jj0 = (lane & 15);
        if (jj0 >= deg) jj0 = deg - 1;
        int si = epair[lo + jj0].y;

        for (int base = 0; base < deg; base += 16) {
            // issue all gathers of this chunk (wave-uniform scalar base per edge)
            ushort2 u[16];
#pragma unroll
            for (int j = 0; j < 16; ++j) {
                if (base + j < deg) {
                    int s = __builtin_amdgcn_readlane(si, j);
                    u[j] = *(const ushort2*)(el_bf + (size_t)s * HD + l2);
                }
            }
            // prefetch next chunk's indices (hides index-load latency under compute)
            int si_nxt = si;
            if (base + 16 < deg) {
                int jj = base + 16 + (lane & 15);
                if (jj >= deg) jj = deg - 1;
                si_nxt = epair[lo + jj].y;
            }
            // process chunk: per-edge, branchless online softmax (proven shape)
#pragma unroll
            for (int j = 0; j < 16; ++j) {
                if (base + j < deg) {
                    float evx = bf2f(u[j].x), evy = bf2f(u[j].y);
                    float x0 = evx + rv.x; x0 = fmaxf(x0, NEG * x0);
                    float x1 = evy + rv.y; x1 = fmaxf(x1, NEG * x1);
                    float p = x0 * a0 + x1 * a1;        // log2-domain score
                    p += __shfl_xor(p, 1, 16);
                    p += __shfl_xor(p, 2, 16);
                    p += __shfl_xor(p, 4, 16);
                    p += __shfl_xor(p, 8, 16);
                    if ((lane & 15) == 0) spw[(base + j) * NH + hh] = p;
                    float mn = fmaxf(m, p);
                    float sc = exp2f(m - mn);
                    float w  = exp2f(p - mn);
                    lsum = lsum * sc + w;
                    acc0 = acc0 * sc + w * evx;
                    acc1 = acc1 * sc + w * evy;
                    m = mn;
                }
            }
            si = si_nxt;
        }
    } else if (deg > DEGCAP) {
        // fallback pass 1: online softmax only (no score stash)
        ushort2 u = {0,0};
        { int s_ = epair[lo].y; u = *(const ushort2*)(el_bf + (size_t)s_ * HD + l2); }
        for (int i = lo; i < hi; ++i) {
            float evx = bf2f(u.x), evy = bf2f(u.y);
            if (i + 1 < hi) { int s_ = epair[i + 1].y;
                u = *(const ushort2*)(el_bf + (size_t)s_ * HD + l2); }
            float x0 = evx + rv.x; x0 = fmaxf(x0, NEG * x0);
            float x1 = evy + rv.y; x1 = fmaxf(x1, NEG * x1);
            float p = x0 * a0 + x1 * a1;
            p += __shfl_xor(p, 1, 16);
            p += __shfl_xor(p, 2, 16);
            p += __shfl_xor(p, 4, 16);
            p += __shfl_xor(p, 8, 16);
            float mn = fmaxf(m, p);
            float sc = exp2f(m - mn);
            float w  = exp2f(p - mn);
            lsum = lsum * sc + w;
            acc0 = acc0 * sc + w * evx;
            acc1 = acc1 * sc + w * evy;
            m = mn;
        }
    }

    // write aggregated features
    float2 o;
    if (deg == 0) { o.x = 0.0f; o.y = 0.0f; }
    else { float inv = 1.0f / lsum; o.x = acc0 * inv; o.y = acc1 * inv; }
    *(float2*)(out_feat + (size_t)n * HD + l2) = o;

    if (deg == 0) return;

    // normalize + write attention weights
    float inv = 1.0f / lsum;
    if (deg <= DEGCAP) {
        // broadcast (m, inv) of head (lane&3) from its group (values uniform in group)
        float mh   = __shfl(m,   (lane & 3) << 4, 64);
        float invh = __shfl(inv, (lane & 3) << 4, 64);
        for (int q = (lane >> 2); q < deg; q += 16) {
            int e = epair[lo + q].x;
            float p = spw[q * NH + (lane & 3)];
            out_a[(size_t)e * NH + (lane & 3)] = exp2f(p - mh) * invh;
        }
    } else {
        // fallback pass 2: recompute scores and write a
        for (int i = lo; i < hi; ++i) {
            int s_ = epair[i].y;
            ushort2 u = *(const ushort2*)(el_bf + (size_t)s_ * HD + l2);
            float evx = bf2f(u.x), evy = bf2f(u.y);
            float x0 = evx + rv.x; x0 = fmaxf(x0, NEG * x0);
            float x1 = evy + rv.y; x1 = fmaxf(x1, NEG * x1);
            float p = x0 * a0 + x1 * a1;
            p += __shfl_xor(p, 1, 16);
            p += __shfl_xor(p, 2, 16);
            p += __shfl_xor(p, 4, 16);
            p += __shfl_xor(p, 8, 16);
            if ((lane & 15) == 0) {
                int e = epair[i].x;
                out_a[(size_t)e * NH + hh] = exp2f(p - m) * inv;
            }
        }
    }
}

extern "C" void kernel_launch(void* const* d_in, const int* in_sizes, int n_in,
                              void* d_out, int out_size, void* d_ws, size_t ws_size,
                              hipStream_t stream) {
    const float* h    = (const float*)d_in[0];
    const int*   src  = (const int*)d_in[1];
    const int*   dst  = (const int*)d_in[2];
    const float* Wsrc = (const float*)d_in[3];
    const float* bsrc = (const float*)d_in[4];
    const float* Wdst = (const float*)d_in[5];
    const float* bdst = (const float*)d_in[6];
    const float* attn = (const float*)d_in[7];

    float* out_feat = (float*)d_out;                       // N*128
    float* out_a    = out_feat + (size_t)NNODES * HD;      // E*4

    // workspace layout (16B-aligned chunks), ~45 MB total
    float*  er       = (float*)d_ws;                         // N*128 f32 (25.6 MB)
    ushort* Wt       = (ushort*)(er + (size_t)NNODES * HD);  // 256*256 bf16
    ushort* el_bf    = Wt + 2 * HD * INDIM;                  // N*128 bf16 (12.8 MB)
    int*    cnt_work = (int*)(el_bf + (size_t)NNODES * HD);  // N
    int2*   epair    = (int2*)(cnt_work + NNODES);           // E {eidx, esrc} (6.4 MB)
    int*    rowptr   = (int*)(epair + NEDGES);               // N+1
    int*    partials = rowptr + NNODES + 1;                  // SCAN_B

    // 1) fusedPre: clear cnt | W convert+transpose
    fusedPre_kernel<<<CLR_BLKS + CONVW_BLKS, 256, 0, stream>>>(
        cnt_work, Wsrc, Wdst, Wt);

    // 2) hist (non-returning atomics)
    hist_kernel<<<HIST_BLKS, 256, 0, stream>>>(dst, cnt_work);

    // 3-5) proven 3-kernel scan chain -> rowptr + scatter cursors
    scan_partial_kernel<<<SCAN_B, 256, 0, stream>>>(cnt_work, partials);
    scan_offsets_kernel<<<1, 256, 0, stream>>>(partials, rowptr);
    scan_final_kernel<<<SCAN_B, 256, 0, stream>>>(cnt_work, partials, rowptr);

    // 6) fusedB: MFMA GEMM 128x256 (el, er) | CSR scatter
    fusedB_kernel<<<GEMM_BLKS + SCAT_BLKS, 256, 0, stream>>>(
        h, Wt, bsrc, bdst, el_bf, er, src, dst, cnt_work, epair);

    // 7) node_fused
    node_fused_kernel<<<(NNODES + 3) / 4, 256, 0, stream>>>(
        el_bf, er, rowptr, epair, attn, out_feat, out_a);
}

// Round 13
// 264.956 us; speedup vs baseline: 2.3719x; 1.0518x over previous
//
#include <hip/hip_runtime.h>
#include <cstdint>
#include <cstddef>

#define NNODES 50000
#define NEDGES 800000
#define INDIM  256
#define HD     128   // H*D
#define NH     4
#define NEG    0.2f
#define LOG2E  1.44269504088896340736f

#define SCAN_B ((NNODES + 255) / 256)   // 196 blocks

// fusedPre partition (clear cnt | conv_w)
#define CLR_BLKS   49                               // 12544 int4 slots >= 12500
#define CONVW_BLKS 64
// hist
#define HIST_BLKS  ((NEDGES + 2047) / 2048)         // 391
// fusedB block partition (gemm 128x256 | scatter 8 edges/thread)
#define GEMM_BLKS  ((NNODES + 127) / 128)           // 391
#define SCAT_BLKS  ((NEDGES + 2047) / 2048)         // 391

typedef __attribute__((ext_vector_type(8))) short   short8;   // 8 bf16 (4 VGPRs)
typedef __attribute__((ext_vector_type(8))) ushort  ushort8;
typedef __attribute__((ext_vector_type(4))) float   floatx4;

// fast hardware exp2: single v_exp_f32 (exp2f() is the libm-accurate path and
// cost +8 VGPR / +18% VALU cycles in r12 -- do not use it here)
#define EXP2(x) __builtin_amdgcn_exp2f(x)

// f32 -> bf16 (round-to-nearest-even), raw bits
__device__ __forceinline__ ushort f2bf(float f) {
    unsigned u = __float_as_uint(f);
    unsigned r = u + 0x7fffu + ((u >> 16) & 1u);
    return (ushort)(r >> 16);
}
__device__ __forceinline__ float bf2f(ushort u) {
    return __uint_as_float(((unsigned)u) << 16);
}

// LDS chunk swizzle: conflict-free staging writes + fragment reads
__device__ __forceinline__ int swz(int c) { return c ^ ((c >> 4) & 7); }

// ================= fusedPre: clear cnt | W convert+transpose =================
__global__ __launch_bounds__(256) void fusedPre_kernel(
        int* __restrict__ cnt_work,
        const float* __restrict__ Wsrc, const float* __restrict__ Wdst,
        ushort* __restrict__ Wt) {
    __shared__ float t[32][33];
    const int bid = blockIdx.x;
    const int tid = threadIdx.x;

    if (bid < CLR_BLKS) {
        int i = bid * 256 + tid;
        if (i < (NNODES + 3) / 4)
            ((int4*)cnt_work)[i] = make_int4(0, 0, 0, 0);
        return;
    }
    // ---- W convert+transpose (LDS-tiled): Wt[n][k] bf16 ----
    int wb = bid - CLR_BLKS;                      // 0..63
    int kb = (wb & 7) * 32, nb = (wb >> 3) * 32;
    int tx = tid & 31, ty = tid >> 5;
    for (int i = ty; i < 32; i += 8) {
        int k = kb + i, n = nb + tx;
        float v = (n < HD) ? Wsrc[(size_t)k * HD + n] : Wdst[(size_t)k * HD + (n - HD)];
        t[i][tx] = v;
    }
    __syncthreads();
    for (int i = ty; i < 32; i += 8) {
        int n = nb + i, k = kb + tx;
        Wt[(size_t)n * INDIM + k] = f2bf(t[tx][i]);
    }
}

// ================= hist: 8 edges/thread, non-returning atomics =================
__global__ __launch_bounds__(256) void hist_kernel(
        const int* __restrict__ dst, int* __restrict__ cnt_work) {
    int base = blockIdx.x * 2048 + threadIdx.x;
    int dd[8];
#pragma unroll
    for (int k = 0; k < 8; ++k) {
        int e = base + k * 256;
        dd[k] = (e < NEDGES) ? dst[e] : -1;
    }
#pragma unroll
    for (int k = 0; k < 8; ++k) {
        if (dd[k] >= 0) atomicAdd(cnt_work + dd[k], 1);
    }
}

// ================= CSR scan: 2-kernel chain =================
// scan_partial: per-block totals. scan_final: each block SUMS partials[0..bid-1]
// itself (196 ints, L2-hot, one LDS tree) -- the 1-block scan_offsets middle
// kernel is gone (one fewer launch + gap).
__global__ __launch_bounds__(256) void scan_partial_kernel(
        const int* __restrict__ cnt, int* __restrict__ partials) {
    __shared__ int lds[256];
    int i = blockIdx.x * 256 + threadIdx.x;
    lds[threadIdx.x] = (i < NNODES) ? cnt[i] : 0;
    __syncthreads();
    for (int off = 128; off > 0; off >>= 1) {
        if (threadIdx.x < off) lds[threadIdx.x] += lds[threadIdx.x + off];
        __syncthreads();
    }
    if (threadIdx.x == 0) partials[blockIdx.x] = lds[0];
}

__global__ __launch_bounds__(256) void scan_final_kernel(
        int* __restrict__ cnt_work, const int* __restrict__ partials,
        int* __restrict__ rowptr) {
    __shared__ int lds[256];
    __shared__ int sh_prefix;
    const int t = threadIdx.x;
    const int bid = blockIdx.x;

    // prefix = sum of partials[0..bid-1]  (bid <= 195 < 256)
    int pv = (t < bid) ? partials[t] : 0;
    lds[t] = pv;
    __syncthreads();
    for (int off = 128; off > 0; off >>= 1) {
        if (t < off) lds[t] += lds[t + off];
        __syncthreads();
    }
    if (t == 0) sh_prefix = lds[0];
    __syncthreads();
    const int prefix = sh_prefix;
    __syncthreads();                       // lds reuse barrier

    const int i = bid * 256 + t;
    int v = (i < NNODES) ? cnt_work[i] : 0;
    lds[t] = v;
    __syncthreads();
    for (int off = 1; off < 256; off <<= 1) {
        int u = (t >= off) ? lds[t - off] : 0;
        __syncthreads();
        lds[t] += u;
        __syncthreads();
    }
    if (i < NNODES) {
        int start = prefix + lds[t] - v;   // exclusive + global prefix
        rowptr[i] = start;
        cnt_work[i] = start;               // scatter cursor
    }
    if (bid == SCAN_B - 1 && t == 255) rowptr[NNODES] = prefix + lds[255];
}

// ================= fusedB: MFMA GEMM (128x256, f32 A direct) | CSR scatter =========
__global__ __launch_bounds__(256, 2) void fusedB_kernel(
        const float* __restrict__ h, const ushort* __restrict__ Wt,
        const float* __restrict__ bsrc, const float* __restrict__ bdst,
        ushort* __restrict__ el_bf, float* __restrict__ er,
        const int* __restrict__ src, const int* __restrict__ dst,
        int* __restrict__ cnt_work, int2* __restrict__ epair) {
    __shared__ ushort As[512 * 8];    // 128 rows x 32 k bf16 (8 KB)
    __shared__ ushort Bs[1024 * 8];   // 256 cols x 32 k bf16 (16 KB)

    const int bid = blockIdx.x;
    const int tid = threadIdx.x;

    if (bid >= GEMM_BLKS) {
        // ---- scatter: build CSR edge list, 8 edges/thread (stride-256, coalesced) ----
        int base = (bid - GEMM_BLKS) * 2048 + tid;
        int ss[8], dd[8], pos[8];
#pragma unroll
        for (int k = 0; k < 8; ++k) {
            int e = base + k * 256;
            if (e < NEDGES) { ss[k] = src[e]; dd[k] = dst[e]; } else dd[k] = -1;
        }
#pragma unroll
        for (int k = 0; k < 8; ++k) {
            if (dd[k] >= 0) pos[k] = atomicAdd(cnt_work + dd[k], 1);
        }
#pragma unroll
        for (int k = 0; k < 8; ++k) {
            int e = base + k * 256;
            if (dd[k] >= 0) epair[pos[k]] = make_int2(e, ss[k]);
        }
        return;
    }

    const int wave = tid >> 6, lane = tid & 63;
    const int row0 = bid * 128;
    const int l15  = lane & 15, quad = lane >> 4;

    floatx4 acc[2][16];
#pragma unroll
    for (int i = 0; i < 2; ++i)
#pragma unroll
        for (int j = 0; j < 16; ++j) acc[i][j] = (floatx4){0.f, 0.f, 0.f, 0.f};

    for (int kk = 0; kk < INDIM; kk += 32) {
        // ---- A staging: 512 chunks of 8, f32 source + convert ----
#pragma unroll
        for (int it = 0; it < 2; ++it) {
            int idx = tid + it * 256;    // 0..511
            int r = idx >> 2;            // 0..127 (row)
            int kq = idx & 3;            // k-quad (8 elems)
            int c = (r >> 4) * 64 + kq * 16 + (r & 15);
            int grow = row0 + r;
            ushort8 aw = (ushort8){0,0,0,0,0,0,0,0};
            if (grow < NNODES) {
                const float* p = h + (size_t)grow * INDIM + kk + kq * 8;
                float4 v0 = *(const float4*)p;
                float4 v1 = *(const float4*)(p + 4);
                aw[0] = f2bf(v0.x); aw[1] = f2bf(v0.y); aw[2] = f2bf(v0.z); aw[3] = f2bf(v0.w);
                aw[4] = f2bf(v1.x); aw[5] = f2bf(v1.y); aw[6] = f2bf(v1.z); aw[7] = f2bf(v1.w);
            }
            *(ushort8*)(As + swz(c) * 8) = aw;
        }
        // ---- B staging: 1024 chunks of 8 (256 cols) ----
#pragma unroll
        for (int it = 0; it < 4; ++it) {
            int idx = tid + it * 256;    // 0..1023
            int r = idx >> 2;            // 0..255 (col)
            int kq = idx & 3;
            int c = (r >> 4) * 64 + kq * 16 + (r & 15);   // 0..1023
            ushort8 bw = *(const ushort8*)(Wt + (size_t)r * INDIM + kk + kq * 8);
            *(ushort8*)(Bs + swz(c) * 8) = bw;
        }
        __syncthreads();

        short8 af[2];
#pragma unroll
        for (int tm = 0; tm < 2; ++tm) {
            int c = (wave * 2 + tm) * 64 + quad * 16 + l15;
            af[tm] = *(const short8*)(As + swz(c) * 8);
        }
#pragma unroll
        for (int tn = 0; tn < 16; ++tn) {
            int c = tn * 64 + quad * 16 + l15;
            short8 bfr = *(const short8*)(Bs + swz(c) * 8);
            acc[0][tn] = __builtin_amdgcn_mfma_f32_16x16x32_bf16(af[0], bfr, acc[0][tn], 0, 0, 0);
            acc[1][tn] = __builtin_amdgcn_mfma_f32_16x16x32_bf16(af[1], bfr, acc[1][tn], 0, 0, 0);
        }
        __syncthreads();
    }

    // epilogue: C/D layout col=lane&15, row=quad*4+reg
#pragma unroll
    for (int tn = 0; tn < 8; ++tn) {
        int col = tn * 16 + l15;              // 0..127 -> el
        float bias = bsrc[col];
#pragma unroll
        for (int tm = 0; tm < 2; ++tm)
#pragma unroll
            for (int reg = 0; reg < 4; ++reg) {
                int row = row0 + wave * 32 + tm * 16 + quad * 4 + reg;
                if (row < NNODES)
                    el_bf[(size_t)row * HD + col] = f2bf(acc[tm][tn][reg] + bias);
            }
    }
#pragma unroll
    for (int tn = 8; tn < 16; ++tn) {
        int col = tn * 16 + l15 - HD;         // 0..127 -> er
        float bias = bdst[col];
#pragma unroll
        for (int tm = 0; tm < 2; ++tm)
#pragma unroll
            for (int reg = 0; reg < 4; ++reg) {
                int row = row0 + wave * 32 + tm * 16 + quad * 4 + reg;
                if (row < NNODES)
                    er[(size_t)row * HD + col] = acc[tm][tn][reg] + bias;
            }
    }
}

// ================= node_fused: r5-proven branchless body + exp2 rebasing (HW exp2) ==
// one wave per node; lane l owns dims 2l,2l+1; head hh = l>>4. CSR int2 epair.
// a0,a1 pre-scaled by log2(e) -> scores in log2 domain; EXP2 = raw v_exp_f32
// builtin (single instruction). Body shape is the proven 71-73us form -- do NOT
// restructure (batched rewrites, defer-max, buckets all regressed).
#define DEGCAP 128

__global__ __launch_bounds__(256) void node_fused_kernel(
        const ushort* __restrict__ el_bf, const float* __restrict__ er,
        const int* __restrict__ rowptr, const int2* __restrict__ epair,
        const float* __restrict__ attn,
        float* __restrict__ out_feat, float* __restrict__ out_a) {
    __shared__ float sp[4][DEGCAP * NH];   // 2 KB per wave

    const int wv = threadIdx.x >> 6;
    const int n = blockIdx.x * 4 + wv;
    if (n >= NNODES) return;
    const int lane = threadIdx.x & 63;
    const int hh = lane >> 4;
    const int lo = rowptr[n], hi = rowptr[n + 1];
    const int deg = hi - lo;
    float* spw = sp[wv];
    const int l2 = lane * 2;

    const float2 rv = *(const float2*)(er + (size_t)n * HD + l2);
    const float a0 = attn[l2] * LOG2E, a1 = attn[l2 + 1] * LOG2E;

    float m = -3.4e38f, lsum = 0.0f, acc0 = 0.0f, acc1 = 0.0f;

    if (deg > 0 && deg <= DEGCAP) {
        // preload first chunk of up to 16 edge-source indices (coalesced, clamped)
        int jj0 = (lane & 15);
        if (jj0 >= deg) jj0 = deg - 1;
        int si = epair[lo + jj0].y;

        for (int base = 0; base < deg; base += 16) {
            // issue all gathers of this chunk (wave-uniform scalar base per edge)
            ushort2 u[16];
#pragma unroll
            for (int j = 0; j < 16; ++j) {
                if (base + j < deg) {
                    int s = __builtin_amdgcn_readlane(si, j);
                    u[j] = *(const ushort2*)(el_bf + (size_t)s * HD + l2);
                }
            }
            // prefetch next chunk's indices (hides index-load latency under compute)
            int si_nxt = si;
            if (base + 16 < deg) {
                int jj = base + 16 + (lane & 15);
                if (jj >= deg) jj = deg - 1;
                si_nxt = epair[lo + jj].y;
            }
            // process chunk: per-edge, branchless online softmax (proven shape)
#pragma unroll
            for (int j = 0; j < 16; ++j) {
                if (base + j < deg) {
                    float evx = bf2f(u[j].x), evy = bf2f(u[j].y);
                    float x0 = evx + rv.x; x0 = fmaxf(x0, NEG * x0);
                    float x1 = evy + rv.y; x1 = fmaxf(x1, NEG * x1);
                    float p = x0 * a0 + x1 * a1;        // log2-domain score
                    p += __shfl_xor(p, 1, 16);
                    p += __shfl_xor(p, 2, 16);
                    p += __shfl_xor(p, 4, 16);
                    p += __shfl_xor(p, 8, 16);
                    if ((lane & 15) == 0) spw[(base + j) * NH + hh] = p;
                    float mn = fmaxf(m, p);
                    float sc = EXP2(m - mn);
                    float w  = EXP2(p - mn);
                    lsum = lsum * sc + w;
                    acc0 = acc0 * sc + w * evx;
                    acc1 = acc1 * sc + w * evy;
                    m = mn;
                }
            }
            si = si_nxt;
        }
    } else if (deg > DEGCAP) {
        // fallback pass 1: online softmax only (no score stash)
        ushort2 u = {0,0};
        { int s_ = epair[lo].y; u = *(const ushort2*)(el_bf + (size_t)s_ * HD + l2); }
        for (int i = lo; i < hi; ++i) {
            float evx = bf2f(u.x), evy = bf2f(u.y);
            if (i + 1 < hi) { int s_ = epair[i + 1].y;
                u = *(const ushort2*)(el_bf + (size_t)s_ * HD + l2); }
            float x0 = evx + rv.x; x0 = fmaxf(x0, NEG * x0);
            float x1 = evy + rv.y; x1 = fmaxf(x1, NEG * x1);
            float p = x0 * a0 + x1 * a1;
            p += __shfl_xor(p, 1, 16);
            p += __shfl_xor(p, 2, 16);
            p += __shfl_xor(p, 4, 16);
            p += __shfl_xor(p, 8, 16);
            float mn = fmaxf(m, p);
            float sc = EXP2(m - mn);
            float w  = EXP2(p - mn);
            lsum = lsum * sc + w;
            acc0 = acc0 * sc + w * evx;
            acc1 = acc1 * sc + w * evy;
            m = mn;
        }
    }

    // write aggregated features
    float2 o;
    if (deg == 0) { o.x = 0.0f; o.y = 0.0f; }
    else { float inv = 1.0f / lsum; o.x = acc0 * inv; o.y = acc1 * inv; }
    *(float2*)(out_feat + (size_t)n * HD + l2) = o;

    if (deg == 0) return;

    // normalize + write attention weights
    float inv = 1.0f / lsum;
    if (deg <= DEGCAP) {
        // broadcast (m, inv) of head (lane&3) from its group (values uniform in group)
        float mh   = __shfl(m,   (lane & 3) << 4, 64);
        float invh = __shfl(inv, (lane & 3) << 4, 64);
        for (int q = (lane >> 2); q < deg; q += 16) {
            int e = epair[lo + q].x;
            float p = spw[q * NH + (lane & 3)];
            out_a[(size_t)e * NH + (lane & 3)] = EXP2(p - mh) * invh;
        }
    } else {
        // fallback pass 2: recompute scores and write a
        for (int i = lo; i < hi; ++i) {
            int s_ = epair[i].y;
            ushort2 u = *(const ushort2*)(el_bf + (size_t)s_ * HD + l2);
            float evx = bf2f(u.x), evy = bf2f(u.y);
            float x0 = evx + rv.x; x0 = fmaxf(x0, NEG * x0);
            float x1 = evy + rv.y; x1 = fmaxf(x1, NEG * x1);
            float p = x0 * a0 + x1 * a1;
            p += __shfl_xor(p, 1, 16);
            p += __shfl_xor(p, 2, 16);
            p += __shfl_xor(p, 4, 16);
            p += __shfl_xor(p, 8, 16);
            if ((lane & 15) == 0) {
                int e = epair[i].x;
                out_a[(size_t)e * NH + hh] = EXP2(p - m) * inv;
            }
        }
    }
}

extern "C" void kernel_launch(void* const* d_in, const int* in_sizes, int n_in,
                              void* d_out, int out_size, void* d_ws, size_t ws_size,
                              hipStream_t stream) {
    const float* h    = (const float*)d_in[0];
    const int*   src  = (const int*)d_in[1];
    const int*   dst  = (const int*)d_in[2];
    const float* Wsrc = (const float*)d_in[3];
    const float* bsrc = (const float*)d_in[4];
    const float* Wdst = (const float*)d_in[5];
    const float* bdst = (const float*)d_in[6];
    const float* attn = (const float*)d_in[7];

    float* out_feat = (float*)d_out;                       // N*128
    float* out_a    = out_feat + (size_t)NNODES * HD;      // E*4

    // workspace layout (16B-aligned chunks), ~45 MB total
    float*  er       = (float*)d_ws;                         // N*128 f32 (25.6 MB)
    ushort* Wt       = (ushort*)(er + (size_t)NNODES * HD);  // 256*256 bf16
    ushort* el_bf    = Wt + 2 * HD * INDIM;                  // N*128 bf16 (12.8 MB)
    int*    cnt_work = (int*)(el_bf + (size_t)NNODES * HD);  // N
    int2*   epair    = (int2*)(cnt_work + NNODES);           // E {eidx, esrc} (6.4 MB)
    int*    rowptr   = (int*)(epair + NEDGES);               // N+1
    int*    partials = rowptr + NNODES + 1;                  // SCAN_B

    // 1) fusedPre: clear cnt | W convert+transpose
    fusedPre_kernel<<<CLR_BLKS + CONVW_BLKS, 256, 0, stream>>>(
        cnt_work, Wsrc, Wdst, Wt);

    // 2) hist (non-returning atomics)
    hist_kernel<<<HIST_BLKS, 256, 0, stream>>>(dst, cnt_work);

    // 3-4) 2-kernel scan chain -> rowptr + scatter cursors
    scan_partial_kernel<<<SCAN_B, 256, 0, stream>>>(cnt_work, partials);
    scan_final_kernel<<<SCAN_B, 256, 0, stream>>>(cnt_work, partials, rowptr);

    // 5) fusedB: MFMA GEMM 128x256 (el, er) | CSR scatter
    fusedB_kernel<<<GEMM_BLKS + SCAT_BLKS, 256, 0, stream>>>(
        h, Wt, bsrc, bdst, el_bf, er, src, dst, cnt_work, epair);

    // 6) node_fused
    node_fused_kernel<<<(NNODES + 3) / 4, 256, 0, stream>>>(
        el_bf, er, rowptr, epair, attn, out_feat, out_a);
}